// Round 12
// baseline (299.353 us; speedup 1.0000x reference)
//
#include <hip/hip_runtime.h>
#include <cstddef>
#include <cstring>

typedef _Float16 h8 __attribute__((ext_vector_type(8)));
typedef _Float16 h4v __attribute__((ext_vector_type(4)));
typedef float f4 __attribute__((ext_vector_type(4)));
typedef unsigned int u32;
typedef unsigned short u16;

#define MTOT 409600.0f

// ---- d_out scratch offsets (floats); overwritten by k_final at the end ----
#define DO_XM  15360000            // [128][64][25] = 204,800
#define DO_GP  15564800            // [256][4096] = 1,048,576
#define DO_GR  16613376            // reduced Gram [4096] + M1 [64]

// ---- ws float offsets ----
#define WS_OB16 0               // f16 [128][64][128][25] = 13,107,200 floats
#define WS_ATT  13631488        // f16 [128][3][64][25][32]
#define WS_ATTB 23461888        // f32 [128][64][25]
#define WS_BN2P 23666688        // f32 [1024][128]
#define WS_PAR  23827456        // f32 a2[64] b2c[64] a1[192] b1c[192] = 512
#define WS_CSN  23828000        // f32 [600]

// f16-unit offsets (2x float offsets)
#define ATT_H 27262976
#define NAB_H 47595520          // f16 [3][8][32][32]
#define WA_H  47622144          // f16 [3][64][64]
#define W3_H  47634432          // f16 [3][64][64]
#define EW_H  47646720          // f16 [64][128]

#define LDS_DYN 116736   // XsT[400][64]f16 (51200) + H[64][16][32]f16 (65536)

// ============ K1: Gram partials via MFMA + register-prefetch + fused xm ============
// xm fused as MFMA with register-built indicator B (NO LDS atomics — round-8 lesson).
// Wave w: h = w>>2 selects v-half; reuses Gram's af fragment; 1 extra MFMA per kk.
__global__ __launch_bounds__(512) void k_gram(const float* __restrict__ x0,
                                              float* __restrict__ dsc) {
  __shared__ _Float16 Xs[64 * 128];  // 16 KB, row=256B, XOR-swizzled
  char* smb = (char*)Xs;
  int bid = blockIdx.x, tid = threadIdx.x;
  int n = bid >> 1, sh = bid & 1;
  int base = sh * 1536;
  int niter = sh ? 13 : 12;          // 1536 + 1664 = 3200
  const float* xb = x0 + (size_t)n * 204800;
  int wid = tid >> 6, lane = tid & 63, l15 = lane & 15, l4 = lane >> 4;
  int ca = (wid & 3) * 16;
  int jb0 = (wid >> 2) * 2;
  f4 acc[2] = {{0.f, 0.f, 0.f, 0.f}, {0.f, 0.f, 0.f, 0.f}};
  f4 accxm = {0.f, 0.f, 0.f, 0.f};
  int xm_v = l15 + (wid >> 2) * 16;  // matrix column -> v index (>=25 lanes inert)
  int sc = tid >> 3, scol = (tid & 7) * 16;
  int swz = (sc & 7) << 4;
  int mmod = (base + l4 * 8) % 25;   // s-mod-25 tracker for this lane's k-octet
  // prefetch iteration 0
  float4 pf0, pf1, pf2, pf3;
  {
    const float* src = xb + sc * 3200 + base + scol;
    pf0 = *(const float4*)(src);
    pf1 = *(const float4*)(src + 4);
    pf2 = *(const float4*)(src + 8);
    pf3 = *(const float4*)(src + 12);
  }
  for (int it = 0; it < niter; ++it) {
    __syncthreads();
    {
      h4v hv;
      hv = (h4v){(_Float16)pf0.x, (_Float16)pf0.y, (_Float16)pf0.z, (_Float16)pf0.w};
      *(h4v*)(smb + sc * 256 + (((scol + 0) * 2) ^ swz)) = hv;
      hv = (h4v){(_Float16)pf1.x, (_Float16)pf1.y, (_Float16)pf1.z, (_Float16)pf1.w};
      *(h4v*)(smb + sc * 256 + (((scol + 4) * 2) ^ swz)) = hv;
      hv = (h4v){(_Float16)pf2.x, (_Float16)pf2.y, (_Float16)pf2.z, (_Float16)pf2.w};
      *(h4v*)(smb + sc * 256 + (((scol + 8) * 2) ^ swz)) = hv;
      hv = (h4v){(_Float16)pf3.x, (_Float16)pf3.y, (_Float16)pf3.z, (_Float16)pf3.w};
      *(h4v*)(smb + sc * 256 + (((scol + 12) * 2) ^ swz)) = hv;
    }
    __syncthreads();
    if (it + 1 < niter) {  // issue next-iter loads; latency hides under MFMAs
      const float* src = xb + sc * 3200 + base + (it + 1) * 128 + scol;
      pf0 = *(const float4*)(src);
      pf1 = *(const float4*)(src + 4);
      pf2 = *(const float4*)(src + 8);
      pf3 = *(const float4*)(src + 12);
    }
    int cm = mmod;
#pragma unroll
    for (int kk = 0; kk < 4; ++kk) {
      int kb = kk * 64 + l4 * 16;
      int arow = ca + l15;
      h8 af = *(const h8*)(smb + arow * 256 + (kb ^ ((arow & 7) << 4)));
#pragma unroll
      for (int j = 0; j < 2; ++j) {
        int brow = (jb0 + j) * 16 + l15;
        h8 bf = *(const h8*)(smb + brow * 256 + (kb ^ ((brow & 7) << 4)));
        acc[j] = __builtin_amdgcn_mfma_f32_16x16x32_f16(af, bf, acc[j], 0, 0, 0);
      }
      // xm: indicator B-fragment (f16 1/128 = 0x2000 where s%25 == xm_v)
      union { u32 w[4]; h8 v; } bx;
      int t = cm;
#pragma unroll
      for (int p = 0; p < 4; ++p) {
        int t0 = t >= 25 ? t - 25 : t;
        int t1 = (t + 1) >= 25 ? t - 24 : t + 1;
        bx.w[p] = (t0 == xm_v ? 0x2000u : 0u) | (t1 == xm_v ? 0x20000000u : 0u);
        t += 2;
      }
      accxm = __builtin_amdgcn_mfma_f32_16x16x32_f16(af, bx.v, accxm, 0, 0, 0);
      cm += 7; if (cm >= 25) cm -= 25;   // +32 mod 25 per kk
    }
    mmod += 3; if (mmod >= 25) mmod -= 25;  // +128 mod 25 per iter
  }
  float* o = dsc + DO_GP + (size_t)bid * 4096;
#pragma unroll
  for (int j = 0; j < 2; ++j)
#pragma unroll
    for (int q = 0; q < 4; ++q)
      o[(ca + l4 * 4 + q) * 64 + (jb0 + j) * 16 + l15] = acc[j][q];
  if (xm_v < 25) {
#pragma unroll
    for (int q = 0; q < 4; ++q) {
      int c = ca + l4 * 4 + q;
      atomicAdd(&dsc[DO_XM + (size_t)n * 1600 + c * 25 + xm_v], accxm[q]);
    }
  }
}

// ============ K1b: reduce 256 Gram partials + M1 from xm ============
__global__ __launch_bounds__(256) void k_gred(float* __restrict__ dsc) {
  int bid = blockIdx.x, tid = threadIdx.x;
  if (bid < 16) {
    int idx = bid * 256 + tid;
    const float* gp = dsc + DO_GP;
    float s0 = 0.f, s1 = 0.f, s2 = 0.f, s3 = 0.f;
    for (int b = 0; b < 256; b += 4) {
      s0 += gp[(size_t)b * 4096 + idx];
      s1 += gp[(size_t)(b + 1) * 4096 + idx];
      s2 += gp[(size_t)(b + 2) * 4096 + idx];
      s3 += gp[(size_t)(b + 3) * 4096 + idx];
    }
    dsc[DO_GR + idx] = (s0 + s1) + (s2 + s3);
  } else {
    __shared__ float red[64][5];
    int c = tid >> 2, j = tid & 3;
    float s = 0.f;
    for (int nn = j; nn < 128; nn += 4) {
      const float* xmp = dsc + DO_XM + (size_t)(nn * 64 + c) * 25;
      for (int v = 0; v < 25; ++v) s += xmp[v];
    }
    red[c][j] = s;
    __syncthreads();
    if (j == 0)
      dsc[DO_GR + 4096 + c] = 128.f * (red[c][0] + red[c][1] + red[c][2] + red[c][3]);
  }
}

// ===== K2a: parallel prep — norm_A->NAB f16 + csn; W3/EW f16 copies =====
__global__ __launch_bounds__(256) void k_prep(const float* __restrict__ DA,
                                              const float* __restrict__ w3,
                                              const float* __restrict__ ensw,
                                              float* __restrict__ wsF) {
  int bid = blockIdx.x, tid = threadIdx.x;
  _Float16* wsH = (_Float16*)wsF;
  if (bid < 3) {
    if (tid < 200) {
      int k = bid, g = tid / 25, w = tid % 25;
      const float* base = DA + (k * 8 + g) * 625 + w;
      float s = 0.f;
      for (int v = 0; v < 25; v++) s += base[v * 25];
      float inv = 1.0f / (s + 0.001f);
      wsF[WS_CSN + k * 200 + g * 25 + w] = s * inv;
      _Float16* dst = wsH + NAB_H + (size_t)((k * 8 + g) * 32 + w) * 32;
      for (int v = 0; v < 25; v++) dst[v] = (_Float16)(base[v * 25] * inv);
      for (int v = 25; v < 32; v++) dst[v] = (_Float16)0.f;
    }
  } else if (bid == 3) {
    for (int idx = tid; idx < 5376; idx += 256) {  // pad rows w=25..31
      int kg = idx / 224, r = idx % 224;
      int w = 25 + r / 32, v = r & 31;
      wsH[NAB_H + (size_t)(kg * 32 + w) * 32 + v] = (_Float16)0.f;
    }
  } else if (bid < 12) {
    int i0 = (bid - 4) * 1536;
    for (int i = tid; i < 1536; i += 256)
      wsH[W3_H + i0 + i] = (_Float16)w3[i0 + i];
  } else {
    int i0 = (bid - 12) * 2048;
    for (int i = tid; i < 2048; i += 256)
      wsH[EW_H + i0 + i] = (_Float16)ensw[i0 + i];
  }
}

// ===== K2b: BN1 stats (y^T G y per d) + folded WA rows =====
__global__ __launch_bounds__(256) void k_bnstat(const float* __restrict__ dsc,
                                                const float* __restrict__ Lw,
                                                const float* __restrict__ g0,
                                                const float* __restrict__ b0,
                                                float* __restrict__ wsF) {
  __shared__ float Gsh[64 * 66];
  __shared__ float Ly[64][17];
  __shared__ float part[16][17];
  __shared__ float a1L[16];
  int bid = blockIdx.x, tid = threadIdx.x;
  int d0 = bid * 16, dl = tid >> 4, r = tid & 15, d = d0 + dl;
  for (int idx = tid; idx < 4096; idx += 256)
    Gsh[(idx >> 6) * 66 + (idx & 63)] = dsc[DO_GR + idx];
  for (int idx = tid; idx < 1024; idx += 256)
    Ly[idx >> 4][idx & 15] = Lw[(idx >> 4) * 192 + d0 + (idx & 15)];
  __syncthreads();
  float acc = 0.f;
#pragma unroll
  for (int cc = 0; cc < 4; ++cc) {
    int c = r * 4 + cc;
    float h = 0.f;
    for (int c2 = 0; c2 < 64; ++c2) h += Gsh[c * 66 + c2] * Ly[c2][dl];
    acc += Ly[c][dl] * h;
  }
  part[dl][r] = acc;
  __syncthreads();
  if (r == 0) {
    float ex2 = 0.f;
#pragma unroll
    for (int i = 0; i < 16; ++i) ex2 += part[dl][i];
    ex2 *= (1.0f / MTOT);
    float mu = 0.f;
    for (int c = 0; c < 64; ++c) mu += dsc[DO_GR + 4096 + c] * Ly[c][dl];
    mu *= (1.0f / MTOT);
    float var = ex2 - mu * mu;
    float a1 = g0[d] * rsqrtf(var + 1e-5f);
    float b1c = b0[d] - a1 * mu;  // Linear_bias cancels in training-mode BN
    wsF[WS_PAR + 128 + d] = a1;
    wsF[WS_PAR + 320 + d] = b1c;
    a1L[dl] = a1;
  }
  __syncthreads();
  _Float16* wsH = (_Float16*)wsF;
  int k = d >> 6, cg = d & 63;
  float a1v = a1L[dl];
#pragma unroll
  for (int j = 0; j < 4; ++j) {
    int e = r * 4 + j;
    wsH[WA_H + k * 4096 + cg * 64 + e] = (_Float16)(a1v * Lw[e * 192 + d]);
  }
}

// ============ K4: attention -> attT f16 [n][i][c][v=w][u pad32] + attB ============
__global__ __launch_bounds__(256) void k_att(const float* __restrict__ dsc,
    const float* __restrict__ w1, const float* __restrict__ b1,
    const float* __restrict__ w2, const float* __restrict__ b2,
    const float* __restrict__ w4, const float* __restrict__ b4,
    const float* __restrict__ Ag, const float* __restrict__ alpha,
    const float* __restrict__ b3, float* __restrict__ wsF) {
  __shared__ float xms[1600];
  __shared__ float x1s[200];
  __shared__ float x2s[200];
  __shared__ float Td[5000];
  int bid = blockIdx.x, tid = threadIdx.x;
  int n = bid / 3, i = bid % 3;
  for (int idx = tid; idx < 1600; idx += 256)
    xms[idx] = dsc[DO_XM + (size_t)n * 1600 + idx];
  __syncthreads();
  for (int idx = tid; idx < 400; idx += 256) {
    int r = (idx % 200) / 25, u = idx % 25;
    const float* wv = (idx < 200 ? w1 : w2) + (i * 8 + r) * 64;
    float acc = (idx < 200 ? b1 : b2)[i * 8 + r];
    for (int c = 0; c < 64; c++) acc += xms[c * 25 + u] * wv[c];
    if (idx < 200) x1s[r * 25 + u] = acc; else x2s[r * 25 + u] = acc;
  }
  __syncthreads();
  for (int idx = tid; idx < 5000; idx += 256) {
    int r = idx / 625, u = (idx % 625) / 25, w = idx % 25;
    Td[idx] = tanhf(x1s[r * 25 + u] - x2s[r * 25 + w]);
  }
  __syncthreads();
  float al = alpha[0];
  u32* attW = (u32*)wsF;
  for (int p = tid; p < 1600; p += 256) {
    int o = p / 25, w = p % 25;
    float w4r[8];
#pragma unroll
    for (int r = 0; r < 8; r++) w4r[r] = w4[(i * 64 + o) * 8 + r];
    float b4v = b4[i * 64 + o];
    const float* AgW = Ag + i * 625 + w;
    float asum = 0.f;
    size_t rowH = (size_t)ATT_H + ((size_t)((n * 3 + i) * 64 + o) * 25 + w) * 32;
    u32* row = attW + rowH / 2;
    for (int up = 0; up < 16; ++up) {
      u32 word = 0;
#pragma unroll
      for (int h = 0; h < 2; ++h) {
        int u = up * 2 + h;
        float v = 0.f;
        if (u < 25) {
          float acc = b4v;
#pragma unroll
          for (int r = 0; r < 8; r++) acc += w4r[r] * Td[r * 625 + u * 25 + w];
          v = al * acc + AgW[u * 25];
          asum += v;
        }
        union { _Float16 hf; u16 b; } cv;
        cv.hf = (_Float16)v;
        word |= ((u32)cv.b) << (16 * h);
      }
      row[up] = word;
    }
    atomicAdd(&wsF[WS_ATTB + (size_t)n * 1600 + p], b3[i * 64 + o] * asum);
  }
}

// ---- shared device helpers for kAB (1024-thread version) ----
// stageX: round-6 mapping — lanes consecutive in s => coalesced 4-stream reads
__device__ __forceinline__ void stageX(const float* __restrict__ xn, char* sm, int tid) {
  for (int u = tid; u < 6400; u += 1024) {
    int cg = u / 400, s = u - cg * 400;
    int c0 = cg * 4;
    const float* p = xn + c0 * 3200 + s;
    float a = p[0], b = p[3200], c = p[6400], d = p[9600];
    h4v hv = {(_Float16)a, (_Float16)b, (_Float16)c, (_Float16)d};
    *(h4v*)(sm + s * 128 + ((c0 * 2) ^ ((s & 7) << 4))) = hv;
  }
}
__device__ __forceinline__ void zeroHpads(char* sm, int tid) {
  for (int idx = tid; idx < 7168; idx += 1024) {
    int c = idx / 112, r = idx % 112;
    int t = r / 7, u = 25 + r % 7;
    int hs = (((t & 3) ^ ((c >> 2) & 3)) << 4);
    *(_Float16*)(sm + 51200 + c * 1024 + t * 64 + ((u * 2) ^ hs)) = (_Float16)0.f;
  }
}
// 64-row GEMM: H[c][t][u] = sum_e A[c][e] * XsT[s][e]; wave handles (mt, nt0..nt1)
__device__ __forceinline__ void gemm64(const _Float16* __restrict__ Aw, char* sm,
                                       int mt, int nt0, int nt1, int lane) {
  int l15 = lane & 15, l4 = lane >> 4;
  h8 a0 = *(const h8*)(Aw + (mt * 16 + l15) * 64 + l4 * 8);
  h8 a1 = *(const h8*)(Aw + (mt * 16 + l15) * 64 + 32 + l4 * 8);
  int s = nt0 * 16 + l15;
  int t = s / 25, u = s - t * 25;     // one div; incremental after
  int hsc = ((mt * 4 + l4) & 3) << 4; // (c>>2)&3 is q-invariant
  for (int nt = nt0; nt < nt1; ++nt) {
    int sw = (s & 7) << 4;
    const char* rb = sm + s * 128;
    h8 b0 = *(const h8*)(rb + ((l4 * 16) ^ sw));
    h8 b1 = *(const h8*)(rb + ((64 + l4 * 16) ^ sw));
    f4 acc = {0.f, 0.f, 0.f, 0.f};
    acc = __builtin_amdgcn_mfma_f32_16x16x32_f16(a0, b0, acc, 0, 0, 0);
    acc = __builtin_amdgcn_mfma_f32_16x16x32_f16(a1, b1, acc, 0, 0, 0);
    int hs = ((t & 3) << 4) ^ hsc;
    char* wb = sm + 51200 + (mt * 16 + l4 * 4) * 1024 + t * 64 + ((u * 2) ^ hs);
#pragma unroll
    for (int q = 0; q < 4; ++q)
      *(_Float16*)(wb + q * 1024) = (_Float16)acc[q];
    s += 16;
    u += 16;
    if (u >= 25) { u -= 25; ++t; }
  }
}

// ===== kAB: fused — 16 waves: stage x0 once; xb (WA×3 + NAB) and y (W3×3 + attT)
//       in regs; cat in LDS; ensemble GEMM; f16 out_pre + BN2 partials
__global__ __launch_bounds__(1024, 4) void kAB(const float* __restrict__ x0,
                                               float* ws,
                                               const float* __restrict__ ensb) {
  extern __shared__ char sm[];
  __shared__ float redS[128];
  __shared__ float attBs[1600];
  __shared__ float cbS[1600];
  const _Float16* wsH = (const _Float16*)ws;
  int tid = threadIdx.x, bid = blockIdx.x;
  int lb = (bid & 7) * 128 + (bid >> 3);
  int n = lb >> 3, tile = lb & 7;
  int wid = tid >> 6, lane = tid & 63, l15 = lane & 15, l4 = lane >> 4;
  int mt = wid & 3, q4 = wid >> 2, g = wid & 7;
  int nt0 = q4 ? 1 + 6 * q4 : 0;
  int nt1 = q4 ? nt0 + 6 : 7;
  if (tid < 128) redS[tid] = 0.f;
  for (int idx = tid; idx < 1600; idx += 1024)
    attBs[idx] = ws[WS_ATTB + (size_t)n * 1600 + idx];
  // cb[c][w] = sum_k b1c[k*64+c] * csn[k][c&7][w]  (folded k_cb)
  for (int idx = tid; idx < 1600; idx += 1024) {
    int c = idx / 25, w = idx - c * 25;
    int gg = c & 7;
    float s = 0.f;
#pragma unroll
    for (int k = 0; k < 3; ++k)
      s += ws[WS_PAR + 320 + k * 64 + c] * ws[WS_CSN + k * 200 + gg * 25 + w];
    cbS[idx] = s;
  }
  stageX(x0 + (size_t)n * 204800 + tile * 400, sm, tid);
  zeroHpads(sm, tid);
  __syncthreads();
  f4 accx[4][2], accy[4][2];
#pragma unroll
  for (int a = 0; a < 4; a++)
#pragma unroll
    for (int b = 0; b < 2; b++) {
      accx[a][b] = (f4){0.f, 0.f, 0.f, 0.f};
      accy[a][b] = (f4){0.f, 0.f, 0.f, 0.f};
    }
  // ---- xb branch: 3 × (Linear GEMM; contract with norm_A) ----
  for (int k = 0; k < 3; ++k) {
    gemm64(wsH + WA_H + k * 4096, sm, mt, nt0, nt1, lane);
    __syncthreads();
#pragma unroll
    for (int mt2 = 0; mt2 < 4; ++mt2) {
      int c = mt2 * 16 + wid;
      int hs = (((l15 & 3) ^ ((c >> 2) & 3)) << 4);
      h8 aH = *(const h8*)(sm + 51200 + c * 1024 + l15 * 64 + ((l4 * 16) ^ hs));
#pragma unroll
      for (int nt2 = 0; nt2 < 2; ++nt2) {
        const _Float16* nb = wsH + NAB_H +
            (size_t)((k * 8 + g) * 32 + nt2 * 16 + l15) * 32 + l4 * 8;
        accx[mt2][nt2] = __builtin_amdgcn_mfma_f32_16x16x32_f16(
            aH, *(const h8*)nb, accx[mt2][nt2], 0, 0, 0);
      }
    }
    __syncthreads();
  }
  // ---- y branch: 3 × (x3 GEMM; contract with att) ----
  for (int i = 0; i < 3; ++i) {
    gemm64(wsH + W3_H + i * 4096, sm, mt, nt0, nt1, lane);
    __syncthreads();
#pragma unroll
    for (int mt2 = 0; mt2 < 4; ++mt2) {
      int c = mt2 * 16 + wid;
      int hs = (((l15 & 3) ^ ((c >> 2) & 3)) << 4);
      h8 aX = *(const h8*)(sm + 51200 + c * 1024 + l15 * 64 + ((l4 * 16) ^ hs));
#pragma unroll
      for (int nt2 = 0; nt2 < 2; ++nt2) {
        int v = nt2 * 16 + l15;
        int vc = v < 25 ? v : 0;
        const _Float16* ab = wsH + ATT_H +
            ((size_t)((n * 3 + i) * 64 + c) * 25 + vc) * 32 + l4 * 8;
        accy[mt2][nt2] = __builtin_amdgcn_mfma_f32_16x16x32_f16(
            aX, *(const h8*)ab, accy[mt2][nt2], 0, 0, 0);
      }
    }
    __syncthreads();
  }
  // ---- build catT[400][128] f16 (swizzled) over the XsT/H region ----
#pragma unroll
  for (int mt2 = 0; mt2 < 4; ++mt2) {
    int c = mt2 * 16 + wid;
#pragma unroll
    for (int nt2 = 0; nt2 < 2; ++nt2) {
      int w = nt2 * 16 + l15;
      if (w < 25) {
        float cbv = cbS[c * 25 + w];
        float abv = attBs[c * 25 + w];
#pragma unroll
        for (int q = 0; q < 4; ++q) {
          int t = l4 * 4 + q;
          int s = t * 25 + w;
          int sw = (s & 7) << 4;
          *(_Float16*)(sm + s * 256 + ((c * 2) ^ sw)) =
              (_Float16)(accx[mt2][nt2][q] + cbv);
          *(_Float16*)(sm + s * 256 + (((64 + c) * 2) ^ sw)) =
              (_Float16)(accy[mt2][nt2][q] + abv);
        }
      }
    }
  }
  __syncthreads();
  // ---- ensemble GEMM (K=128) -> f16 out_pre + BN2 partials ----
  h8 ea[4];
#pragma unroll
  for (int ks = 0; ks < 4; ++ks)
    ea[ks] = *(const h8*)(wsH + EW_H + (mt * 16 + l15) * 128 + ks * 32 + l4 * 8);
  float eb[4];
#pragma unroll
  for (int q = 0; q < 4; ++q) eb[q] = ensb[mt * 16 + l4 * 4 + q];
  float lsum[4] = {0.f, 0.f, 0.f, 0.f}, lss[4] = {0.f, 0.f, 0.f, 0.f};
  u16* ob16 = (u16*)ws;
  for (int nt = nt0; nt < nt1; ++nt) {
    int s = nt * 16 + l15;
    int sw = (s & 7) << 4;
    f4 acc = {0.f, 0.f, 0.f, 0.f};
#pragma unroll
    for (int ks = 0; ks < 4; ++ks) {
      h8 b = *(const h8*)(sm + s * 256 + (((ks * 32 + l4 * 8) * 2) ^ sw));
      acc = __builtin_amdgcn_mfma_f32_16x16x32_f16(ea[ks], b, acc, 0, 0, 0);
    }
    size_t ob = (size_t)n * 204800 + (size_t)tile * 400 + s;
#pragma unroll
    for (int q = 0; q < 4; ++q) {
      int o = mt * 16 + l4 * 4 + q;
      union { _Float16 hf; u16 b; } cv;
      cv.hf = (_Float16)(acc[q] + eb[q]);
      ob16[ob + (size_t)o * 3200] = cv.b;
      float val = (float)cv.hf;
      lsum[q] += val;
      lss[q] += val * val;
    }
  }
  // wave-level reduce over the 16 l15 lanes, then one atomic per (l4,q)
#pragma unroll
  for (int q = 0; q < 4; ++q) {
#pragma unroll
    for (int d = 1; d < 16; d <<= 1) {
      lsum[q] += __shfl_xor(lsum[q], d);
      lss[q] += __shfl_xor(lss[q], d);
    }
  }
  if (l15 == 0) {
#pragma unroll
    for (int q = 0; q < 4; ++q) {
      int o = mt * 16 + l4 * 4 + q;
      atomicAdd(&redS[o], lsum[q]);
      atomicAdd(&redS[64 + o], lss[q]);
    }
  }
  __syncthreads();
  if (tid < 64) {
    ws[WS_BN2P + (size_t)bid * 128 + tid * 2] = redS[tid];
    ws[WS_BN2P + (size_t)bid * 128 + tid * 2 + 1] = redS[64 + tid];
  }
}

// ============ K9: BN2 reduce (parallel, one block per channel) ============
__global__ __launch_bounds__(256) void k_bn2(const float* __restrict__ g2,
                                             const float* __restrict__ b2,
                                             float* __restrict__ ws) {
  __shared__ float rs[256], rss[256];
  int o = blockIdx.x, tid = threadIdx.x;
  float s = 0.f, ss = 0.f;
  for (int b = tid; b < 1024; b += 256) {
    s += ws[WS_BN2P + (size_t)b * 128 + o * 2];
    ss += ws[WS_BN2P + (size_t)b * 128 + o * 2 + 1];
  }
  rs[tid] = s; rss[tid] = ss;
  __syncthreads();
  for (int st = 128; st > 0; st >>= 1) {
    if (tid < st) { rs[tid] += rs[tid + st]; rss[tid] += rss[tid + st]; }
    __syncthreads();
  }
  if (tid == 0) {
    float mu = rs[0] / MTOT;
    float var = rss[0] / MTOT - mu * mu;
    float a2 = g2[o] * rsqrtf(var + 1e-5f);
    ws[WS_PAR + o] = a2;
    ws[WS_PAR + 64 + o] = b2[o] - a2 * mu;
  }
}

// ============ K10: BN2 apply + residual + ReLU (reads f16 out_pre) ============
__global__ __launch_bounds__(256) void k_final(const float* __restrict__ x0,
                                               const float* __restrict__ ws,
                                               float* __restrict__ dout) {
  size_t g = (size_t)blockIdx.x * 256 + threadIdx.x;
  h4v p = reinterpret_cast<const h4v*>(ws)[g];
  float4 x = reinterpret_cast<const float4*>(x0)[g];
  int o = (int)((g * 4 / 3200) & 63);
  float a2 = ws[WS_PAR + o], bc = ws[WS_PAR + 64 + o];
  float4 r;
  r.x = fmaxf(fmaf(a2, (float)p[0], bc) + x.x, 0.f);
  r.y = fmaxf(fmaf(a2, (float)p[1], bc) + x.y, 0.f);
  r.z = fmaxf(fmaf(a2, (float)p[2], bc) + x.z, 0.f);
  r.w = fmaxf(fmaf(a2, (float)p[3], bc) + x.w, 0.f);
  reinterpret_cast<float4*>(dout)[g] = r;
}

extern "C" void kernel_launch(void* const* d_in, const int* in_sizes, int n_in,
                              void* d_out, int out_size, void* d_ws, size_t ws_size,
                              hipStream_t stream) {
  const float* x0    = (const float*)d_in[0];
  const float* DA    = (const float*)d_in[1];
  const float* Ag    = (const float*)d_in[2];
  const float* alpha = (const float*)d_in[3];
  const float* w1    = (const float*)d_in[4];
  const float* b1    = (const float*)d_in[5];
  const float* w2    = (const float*)d_in[6];
  const float* b2    = (const float*)d_in[7];
  const float* w3    = (const float*)d_in[8];
  const float* b3    = (const float*)d_in[9];
  const float* w4    = (const float*)d_in[10];
  const float* b4    = (const float*)d_in[11];
  const float* Lw    = (const float*)d_in[12];
  // d_in[13] Linear_bias: cancels under training-mode BN — unused
  const float* g0    = (const float*)d_in[14];
  const float* b0    = (const float*)d_in[15];
  const float* ensw  = (const float*)d_in[16];
  const float* ensb  = (const float*)d_in[17];
  const float* g2    = (const float*)d_in[18];
  const float* b2n   = (const float*)d_in[19];
  float* out = (float*)d_out;
  float* ws  = (float*)d_ws;

  hipFuncSetAttribute((const void*)kAB, hipFuncAttributeMaxDynamicSharedMemorySize, LDS_DYN);

  hipMemsetAsync(ws + WS_ATTB, 0, 204800 * sizeof(float), stream);
  hipMemsetAsync(out + DO_XM, 0, 204800 * sizeof(float), stream);
  k_gram<<<256, 512, 0, stream>>>(x0, out);
  k_prep<<<16, 256, 0, stream>>>(DA, w3, ensw, ws);
  k_att<<<384, 256, 0, stream>>>(out, w1, b1, w2, b2, w4, b4, Ag, alpha, b3, ws);
  k_gred<<<17, 256, 0, stream>>>(out);
  k_bnstat<<<12, 256, 0, stream>>>(out, Lw, g0, b0, ws);
  kAB<<<1024, 1024, LDS_DYN, stream>>>(x0, ws, ensb);
  k_bn2<<<64, 256, 0, stream>>>(g2, b2n, ws);
  k_final<<<25600, 256, 0, stream>>>(x0, ws, out);
}

// Round 14
// 296.879 us; speedup vs baseline: 1.0083x; 1.0083x over previous
//
#include <hip/hip_runtime.h>
#include <cstddef>
#include <cstring>

typedef _Float16 h8 __attribute__((ext_vector_type(8)));
typedef _Float16 h4v __attribute__((ext_vector_type(4)));
typedef float f4 __attribute__((ext_vector_type(4)));
typedef unsigned int u32;
typedef unsigned short u16;

#define MTOT 409600.0f

// ---- d_out scratch offsets (floats); overwritten by k_final at the end ----
#define DO_XM  15360000            // [128][64][25] = 204,800
#define DO_GP  15564800            // [256][4096] = 1,048,576
#define DO_GR  16613376            // reduced Gram [4096] + M1 [64]

// ---- ws float offsets ----
#define WS_OB16 0               // f16 [128][64][128][25] = 13,107,200 floats
#define WS_ATT  13631488        // f16 [128][3][64][25][32]
#define WS_ATTB 23461888        // f32 [128][64][25]
#define WS_BN2P 23666688        // f32 [1024][128]
#define WS_PAR  23827456        // f32 a2[64] b2c[64] a1[192] b1c[192] = 512
#define WS_CSN  23828000        // f32 [600]

// f16-unit offsets (2x float offsets)
#define ATT_H 27262976
#define NAB_H 47595520          // f16 [3][8][32][32]
#define WA_H  47622144          // f16 [3][64][64]
#define W3_H  47634432          // f16 [3][64][64]
#define EW_H  47646720          // f16 [64][128]

#define LDS_DYN 116736   // XsT[400][64]f16 (51200) + H[64][16][32]f16 (65536)

// ============ K1: Gram partials via MFMA + register-prefetch + fused xm ============
// xm fused as MFMA with register-built indicator B (NO LDS atomics — round-8 lesson).
__global__ __launch_bounds__(512) void k_gram(const float* __restrict__ x0,
                                              float* __restrict__ dsc) {
  __shared__ _Float16 Xs[64 * 128];  // 16 KB, row=256B, XOR-swizzled
  char* smb = (char*)Xs;
  int bid = blockIdx.x, tid = threadIdx.x;
  int n = bid >> 1, sh = bid & 1;
  int base = sh * 1536;
  int niter = sh ? 13 : 12;          // 1536 + 1664 = 3200
  const float* xb = x0 + (size_t)n * 204800;
  int wid = tid >> 6, lane = tid & 63, l15 = lane & 15, l4 = lane >> 4;
  int ca = (wid & 3) * 16;
  int jb0 = (wid >> 2) * 2;
  f4 acc[2] = {{0.f, 0.f, 0.f, 0.f}, {0.f, 0.f, 0.f, 0.f}};
  f4 accxm = {0.f, 0.f, 0.f, 0.f};
  int xm_v = l15 + (wid >> 2) * 16;  // matrix column -> v index (>=25 lanes inert)
  int sc = tid >> 3, scol = (tid & 7) * 16;
  int swz = (sc & 7) << 4;
  int mmod = (base + l4 * 8) % 25;   // s-mod-25 tracker for this lane's k-octet
  float4 pf0, pf1, pf2, pf3;
  {
    const float* src = xb + sc * 3200 + base + scol;
    pf0 = *(const float4*)(src);
    pf1 = *(const float4*)(src + 4);
    pf2 = *(const float4*)(src + 8);
    pf3 = *(const float4*)(src + 12);
  }
  for (int it = 0; it < niter; ++it) {
    __syncthreads();
    {
      h4v hv;
      hv = (h4v){(_Float16)pf0.x, (_Float16)pf0.y, (_Float16)pf0.z, (_Float16)pf0.w};
      *(h4v*)(smb + sc * 256 + (((scol + 0) * 2) ^ swz)) = hv;
      hv = (h4v){(_Float16)pf1.x, (_Float16)pf1.y, (_Float16)pf1.z, (_Float16)pf1.w};
      *(h4v*)(smb + sc * 256 + (((scol + 4) * 2) ^ swz)) = hv;
      hv = (h4v){(_Float16)pf2.x, (_Float16)pf2.y, (_Float16)pf2.z, (_Float16)pf2.w};
      *(h4v*)(smb + sc * 256 + (((scol + 8) * 2) ^ swz)) = hv;
      hv = (h4v){(_Float16)pf3.x, (_Float16)pf3.y, (_Float16)pf3.z, (_Float16)pf3.w};
      *(h4v*)(smb + sc * 256 + (((scol + 12) * 2) ^ swz)) = hv;
    }
    __syncthreads();
    if (it + 1 < niter) {
      const float* src = xb + sc * 3200 + base + (it + 1) * 128 + scol;
      pf0 = *(const float4*)(src);
      pf1 = *(const float4*)(src + 4);
      pf2 = *(const float4*)(src + 8);
      pf3 = *(const float4*)(src + 12);
    }
    int cm = mmod;
#pragma unroll
    for (int kk = 0; kk < 4; ++kk) {
      int kb = kk * 64 + l4 * 16;
      int arow = ca + l15;
      h8 af = *(const h8*)(smb + arow * 256 + (kb ^ ((arow & 7) << 4)));
#pragma unroll
      for (int j = 0; j < 2; ++j) {
        int brow = (jb0 + j) * 16 + l15;
        h8 bf = *(const h8*)(smb + brow * 256 + (kb ^ ((brow & 7) << 4)));
        acc[j] = __builtin_amdgcn_mfma_f32_16x16x32_f16(af, bf, acc[j], 0, 0, 0);
      }
      union { u32 w[4]; h8 v; } bx;
      int t = cm;
#pragma unroll
      for (int p = 0; p < 4; ++p) {
        int t0 = t >= 25 ? t - 25 : t;
        int t1 = (t + 1) >= 25 ? t - 24 : t + 1;
        bx.w[p] = (t0 == xm_v ? 0x2000u : 0u) | (t1 == xm_v ? 0x20000000u : 0u);
        t += 2;
      }
      accxm = __builtin_amdgcn_mfma_f32_16x16x32_f16(af, bx.v, accxm, 0, 0, 0);
      cm += 7; if (cm >= 25) cm -= 25;
    }
    mmod += 3; if (mmod >= 25) mmod -= 25;
  }
  float* o = dsc + DO_GP + (size_t)bid * 4096;
#pragma unroll
  for (int j = 0; j < 2; ++j)
#pragma unroll
    for (int q = 0; q < 4; ++q)
      o[(ca + l4 * 4 + q) * 64 + (jb0 + j) * 16 + l15] = acc[j][q];
  if (xm_v < 25) {
#pragma unroll
    for (int q = 0; q < 4; ++q) {
      int c = ca + l4 * 4 + q;
      atomicAdd(&dsc[DO_XM + (size_t)n * 1600 + c * 25 + xm_v], accxm[q]);
    }
  }
}

// ============ K1b: reduce 256 Gram partials + M1 from xm ============
__global__ __launch_bounds__(256) void k_gred(float* __restrict__ dsc) {
  int bid = blockIdx.x, tid = threadIdx.x;
  if (bid < 16) {
    int idx = bid * 256 + tid;
    const float* gp = dsc + DO_GP;
    float s0 = 0.f, s1 = 0.f, s2 = 0.f, s3 = 0.f;
    for (int b = 0; b < 256; b += 4) {
      s0 += gp[(size_t)b * 4096 + idx];
      s1 += gp[(size_t)(b + 1) * 4096 + idx];
      s2 += gp[(size_t)(b + 2) * 4096 + idx];
      s3 += gp[(size_t)(b + 3) * 4096 + idx];
    }
    dsc[DO_GR + idx] = (s0 + s1) + (s2 + s3);
  } else {
    __shared__ float red[64][5];
    int c = tid >> 2, j = tid & 3;
    float s = 0.f;
    for (int nn = j; nn < 128; nn += 4) {
      const float* xmp = dsc + DO_XM + (size_t)(nn * 64 + c) * 25;
      for (int v = 0; v < 25; ++v) s += xmp[v];
    }
    red[c][j] = s;
    __syncthreads();
    if (j == 0)
      dsc[DO_GR + 4096 + c] = 128.f * (red[c][0] + red[c][1] + red[c][2] + red[c][3]);
  }
}

// ===== K2a: parallel prep — norm_A->NAB f16 + csn; W3/EW f16 copies =====
__global__ __launch_bounds__(256) void k_prep(const float* __restrict__ DA,
                                              const float* __restrict__ w3,
                                              const float* __restrict__ ensw,
                                              float* __restrict__ wsF) {
  int bid = blockIdx.x, tid = threadIdx.x;
  _Float16* wsH = (_Float16*)wsF;
  if (bid < 3) {
    if (tid < 200) {
      int k = bid, g = tid / 25, w = tid % 25;
      const float* base = DA + (k * 8 + g) * 625 + w;
      float s = 0.f;
      for (int v = 0; v < 25; v++) s += base[v * 25];
      float inv = 1.0f / (s + 0.001f);
      wsF[WS_CSN + k * 200 + g * 25 + w] = s * inv;
      _Float16* dst = wsH + NAB_H + (size_t)((k * 8 + g) * 32 + w) * 32;
      for (int v = 0; v < 25; v++) dst[v] = (_Float16)(base[v * 25] * inv);
      for (int v = 25; v < 32; v++) dst[v] = (_Float16)0.f;
    }
  } else if (bid == 3) {
    for (int idx = tid; idx < 5376; idx += 256) {  // pad rows w=25..31
      int kg = idx / 224, r = idx % 224;
      int w = 25 + r / 32, v = r & 31;
      wsH[NAB_H + (size_t)(kg * 32 + w) * 32 + v] = (_Float16)0.f;
    }
  } else if (bid < 12) {
    int i0 = (bid - 4) * 1536;
    for (int i = tid; i < 1536; i += 256)
      wsH[W3_H + i0 + i] = (_Float16)w3[i0 + i];
  } else {
    int i0 = (bid - 12) * 2048;
    for (int i = tid; i < 2048; i += 256)
      wsH[EW_H + i0 + i] = (_Float16)ensw[i0 + i];
  }
}

// ===== K2b: BN1 stats (y^T G y per d) + folded WA rows =====
__global__ __launch_bounds__(256) void k_bnstat(const float* __restrict__ dsc,
                                                const float* __restrict__ Lw,
                                                const float* __restrict__ g0,
                                                const float* __restrict__ b0,
                                                float* __restrict__ wsF) {
  __shared__ float Gsh[64 * 66];
  __shared__ float Ly[64][17];
  __shared__ float part[16][17];
  __shared__ float a1L[16];
  int bid = blockIdx.x, tid = threadIdx.x;
  int d0 = bid * 16, dl = tid >> 4, r = tid & 15, d = d0 + dl;
  for (int idx = tid; idx < 4096; idx += 256)
    Gsh[(idx >> 6) * 66 + (idx & 63)] = dsc[DO_GR + idx];
  for (int idx = tid; idx < 1024; idx += 256)
    Ly[idx >> 4][idx & 15] = Lw[(idx >> 4) * 192 + d0 + (idx & 15)];
  __syncthreads();
  float acc = 0.f;
#pragma unroll
  for (int cc = 0; cc < 4; ++cc) {
    int c = r * 4 + cc;
    float h = 0.f;
    for (int c2 = 0; c2 < 64; ++c2) h += Gsh[c * 66 + c2] * Ly[c2][dl];
    acc += Ly[c][dl] * h;
  }
  part[dl][r] = acc;
  __syncthreads();
  if (r == 0) {
    float ex2 = 0.f;
#pragma unroll
    for (int i = 0; i < 16; ++i) ex2 += part[dl][i];
    ex2 *= (1.0f / MTOT);
    float mu = 0.f;
    for (int c = 0; c < 64; ++c) mu += dsc[DO_GR + 4096 + c] * Ly[c][dl];
    mu *= (1.0f / MTOT);
    float var = ex2 - mu * mu;
    float a1 = g0[d] * rsqrtf(var + 1e-5f);
    float b1c = b0[d] - a1 * mu;  // Linear_bias cancels in training-mode BN
    wsF[WS_PAR + 128 + d] = a1;
    wsF[WS_PAR + 320 + d] = b1c;
    a1L[dl] = a1;
  }
  __syncthreads();
  _Float16* wsH = (_Float16*)wsF;
  int k = d >> 6, cg = d & 63;
  float a1v = a1L[dl];
#pragma unroll
  for (int j = 0; j < 4; ++j) {
    int e = r * 4 + j;
    wsH[WA_H + k * 4096 + cg * 64 + e] = (_Float16)(a1v * Lw[e * 192 + d]);
  }
}

// ============ K4: attention -> attT f16 [n][i][c][v=w][u pad32] + attB ============
__global__ __launch_bounds__(256) void k_att(const float* __restrict__ dsc,
    const float* __restrict__ w1, const float* __restrict__ b1,
    const float* __restrict__ w2, const float* __restrict__ b2,
    const float* __restrict__ w4, const float* __restrict__ b4,
    const float* __restrict__ Ag, const float* __restrict__ alpha,
    const float* __restrict__ b3, float* __restrict__ wsF) {
  __shared__ float xms[1600];
  __shared__ float x1s[200];
  __shared__ float x2s[200];
  __shared__ float Td[5000];
  int bid = blockIdx.x, tid = threadIdx.x;
  int n = bid / 3, i = bid % 3;
  for (int idx = tid; idx < 1600; idx += 256)
    xms[idx] = dsc[DO_XM + (size_t)n * 1600 + idx];
  __syncthreads();
  for (int idx = tid; idx < 400; idx += 256) {
    int r = (idx % 200) / 25, u = idx % 25;
    const float* wv = (idx < 200 ? w1 : w2) + (i * 8 + r) * 64;
    float acc = (idx < 200 ? b1 : b2)[i * 8 + r];
    for (int c = 0; c < 64; c++) acc += xms[c * 25 + u] * wv[c];
    if (idx < 200) x1s[r * 25 + u] = acc; else x2s[r * 25 + u] = acc;
  }
  __syncthreads();
  for (int idx = tid; idx < 5000; idx += 256) {
    int r = idx / 625, u = (idx % 625) / 25, w = idx % 25;
    Td[idx] = tanhf(x1s[r * 25 + u] - x2s[r * 25 + w]);
  }
  __syncthreads();
  float al = alpha[0];
  u32* attW = (u32*)wsF;
  for (int p = tid; p < 1600; p += 256) {
    int o = p / 25, w = p % 25;
    float w4r[8];
#pragma unroll
    for (int r = 0; r < 8; r++) w4r[r] = w4[(i * 64 + o) * 8 + r];
    float b4v = b4[i * 64 + o];
    const float* AgW = Ag + i * 625 + w;
    float asum = 0.f;
    size_t rowH = (size_t)ATT_H + ((size_t)((n * 3 + i) * 64 + o) * 25 + w) * 32;
    u32* row = attW + rowH / 2;
    for (int up = 0; up < 16; ++up) {
      u32 word = 0;
#pragma unroll
      for (int h = 0; h < 2; ++h) {
        int u = up * 2 + h;
        float v = 0.f;
        if (u < 25) {
          float acc = b4v;
#pragma unroll
          for (int r = 0; r < 8; r++) acc += w4r[r] * Td[r * 625 + u * 25 + w];
          v = al * acc + AgW[u * 25];
          asum += v;
        }
        union { _Float16 hf; u16 b; } cv;
        cv.hf = (_Float16)v;
        word |= ((u32)cv.b) << (16 * h);
      }
      row[up] = word;
    }
    atomicAdd(&wsF[WS_ATTB + (size_t)n * 1600 + p], b3[i * 64 + o] * asum);
  }
}

// ---- shared device helpers for kAB (1024-thread version) ----
// stageX: round-6 mapping — lanes consecutive in s => coalesced 4-stream reads
__device__ __forceinline__ void stageX(const float* __restrict__ xn, char* sm, int tid) {
  for (int u = tid; u < 6400; u += 1024) {
    int cg = u / 400, s = u - cg * 400;
    int c0 = cg * 4;
    const float* p = xn + c0 * 3200 + s;
    float a = p[0], b = p[3200], c = p[6400], d = p[9600];
    h4v hv = {(_Float16)a, (_Float16)b, (_Float16)c, (_Float16)d};
    *(h4v*)(sm + s * 128 + ((c0 * 2) ^ ((s & 7) << 4))) = hv;
  }
}
__device__ __forceinline__ void zeroHpads(char* sm, int tid) {
  for (int idx = tid; idx < 7168; idx += 1024) {
    int c = idx / 112, r = idx % 112;
    int t = r / 7, u = 25 + r % 7;
    int hs = (((t & 3) ^ ((c >> 2) & 3)) << 4);
    *(_Float16*)(sm + 51200 + c * 1024 + t * 64 + ((u * 2) ^ hs)) = (_Float16)0.f;
  }
}
// 64-row GEMM: H[c][t][u] = sum_e A[c][e] * XsT[s][e]; wave handles (mt, nt0..nt1)
__device__ __forceinline__ void gemm64(const _Float16* __restrict__ Aw, char* sm,
                                       int mt, int nt0, int nt1, int lane) {
  int l15 = lane & 15, l4 = lane >> 4;
  h8 a0 = *(const h8*)(Aw + (mt * 16 + l15) * 64 + l4 * 8);
  h8 a1 = *(const h8*)(Aw + (mt * 16 + l15) * 64 + 32 + l4 * 8);
  int s = nt0 * 16 + l15;
  int t = s / 25, u = s - t * 25;     // one div; incremental after
  int hsc = ((mt * 4 + l4) & 3) << 4; // (c>>2)&3 is q-invariant
  for (int nt = nt0; nt < nt1; ++nt) {
    int sw = (s & 7) << 4;
    const char* rb = sm + s * 128;
    h8 b0 = *(const h8*)(rb + ((l4 * 16) ^ sw));
    h8 b1 = *(const h8*)(rb + ((64 + l4 * 16) ^ sw));
    f4 acc = {0.f, 0.f, 0.f, 0.f};
    acc = __builtin_amdgcn_mfma_f32_16x16x32_f16(a0, b0, acc, 0, 0, 0);
    acc = __builtin_amdgcn_mfma_f32_16x16x32_f16(a1, b1, acc, 0, 0, 0);
    int hs = ((t & 3) << 4) ^ hsc;
    char* wb = sm + 51200 + (mt * 16 + l4 * 4) * 1024 + t * 64 + ((u * 2) ^ hs);
#pragma unroll
    for (int q = 0; q < 4; ++q)
      *(_Float16*)(wb + q * 1024) = (_Float16)acc[q];
    s += 16;
    u += 16;
    if (u >= 25) { u -= 25; ++t; }
  }
}

// ===== kAB: fused — 16 waves: stage x0 once; xb (WA×3 + NAB) and y (W3×3 + attT)
//       in regs; cat in LDS; ensemble GEMM; f16 out_pre + BN2 partials
__global__ __launch_bounds__(1024, 4) void kAB(const float* __restrict__ x0,
                                               float* ws,
                                               const float* __restrict__ ensb) {
  extern __shared__ char sm[];
  __shared__ float redS[128];
  __shared__ float attBs[1600];
  __shared__ float cbS[1600];
  const _Float16* wsH = (const _Float16*)ws;
  int tid = threadIdx.x, bid = blockIdx.x;
  int lb = (bid & 7) * 128 + (bid >> 3);
  int n = lb >> 3, tile = lb & 7;
  int wid = tid >> 6, lane = tid & 63, l15 = lane & 15, l4 = lane >> 4;
  int mt = wid & 3, q4 = wid >> 2, g = wid & 7;
  int nt0 = q4 ? 1 + 6 * q4 : 0;
  int nt1 = q4 ? nt0 + 6 : 7;
  if (tid < 128) redS[tid] = 0.f;
  for (int idx = tid; idx < 1600; idx += 1024)
    attBs[idx] = ws[WS_ATTB + (size_t)n * 1600 + idx];
  // cb[c][w] = sum_k b1c[k*64+c] * csn[k][c&7][w]  (folded k_cb)
  for (int idx = tid; idx < 1600; idx += 1024) {
    int c = idx / 25, w = idx - c * 25;
    int gg = c & 7;
    float s = 0.f;
#pragma unroll
    for (int k = 0; k < 3; ++k)
      s += ws[WS_PAR + 320 + k * 64 + c] * ws[WS_CSN + k * 200 + gg * 25 + w];
    cbS[idx] = s;
  }
  stageX(x0 + (size_t)n * 204800 + tile * 400, sm, tid);
  zeroHpads(sm, tid);
  __syncthreads();
  f4 accx[4][2], accy[4][2];
#pragma unroll
  for (int a = 0; a < 4; a++)
#pragma unroll
    for (int b = 0; b < 2; b++) {
      accx[a][b] = (f4){0.f, 0.f, 0.f, 0.f};
      accy[a][b] = (f4){0.f, 0.f, 0.f, 0.f};
    }
  // ---- xb branch: 3 × (Linear GEMM; contract with norm_A) ----
  for (int k = 0; k < 3; ++k) {
    gemm64(wsH + WA_H + k * 4096, sm, mt, nt0, nt1, lane);
    __syncthreads();
#pragma unroll
    for (int mt2 = 0; mt2 < 4; ++mt2) {
      int c = mt2 * 16 + wid;
      int hs = (((l15 & 3) ^ ((c >> 2) & 3)) << 4);
      h8 aH = *(const h8*)(sm + 51200 + c * 1024 + l15 * 64 + ((l4 * 16) ^ hs));
#pragma unroll
      for (int nt2 = 0; nt2 < 2; ++nt2) {
        const _Float16* nb = wsH + NAB_H +
            (size_t)((k * 8 + g) * 32 + nt2 * 16 + l15) * 32 + l4 * 8;
        accx[mt2][nt2] = __builtin_amdgcn_mfma_f32_16x16x32_f16(
            aH, *(const h8*)nb, accx[mt2][nt2], 0, 0, 0);
      }
    }
    __syncthreads();
  }
  // ---- y branch: 3 × (x3 GEMM; contract with att) ----
  for (int i = 0; i < 3; ++i) {
    gemm64(wsH + W3_H + i * 4096, sm, mt, nt0, nt1, lane);
    __syncthreads();
#pragma unroll
    for (int mt2 = 0; mt2 < 4; ++mt2) {
      int c = mt2 * 16 + wid;
      int hs = (((l15 & 3) ^ ((c >> 2) & 3)) << 4);
      h8 aX = *(const h8*)(sm + 51200 + c * 1024 + l15 * 64 + ((l4 * 16) ^ hs));
#pragma unroll
      for (int nt2 = 0; nt2 < 2; ++nt2) {
        int v = nt2 * 16 + l15;
        int vc = v < 25 ? v : 0;
        const _Float16* ab = wsH + ATT_H +
            ((size_t)((n * 3 + i) * 64 + c) * 25 + vc) * 32 + l4 * 8;
        accy[mt2][nt2] = __builtin_amdgcn_mfma_f32_16x16x32_f16(
            aX, *(const h8*)ab, accy[mt2][nt2], 0, 0, 0);
      }
    }
    __syncthreads();
  }
  // ---- build catT[400][128] f16 (swizzled) over the XsT/H region ----
#pragma unroll
  for (int mt2 = 0; mt2 < 4; ++mt2) {
    int c = mt2 * 16 + wid;
#pragma unroll
    for (int nt2 = 0; nt2 < 2; ++nt2) {
      int w = nt2 * 16 + l15;
      if (w < 25) {
        float cbv = cbS[c * 25 + w];
        float abv = attBs[c * 25 + w];
#pragma unroll
        for (int q = 0; q < 4; ++q) {
          int t = l4 * 4 + q;
          int s = t * 25 + w;
          int sw = (s & 7) << 4;
          *(_Float16*)(sm + s * 256 + ((c * 2) ^ sw)) =
              (_Float16)(accx[mt2][nt2][q] + cbv);
          *(_Float16*)(sm + s * 256 + (((64 + c) * 2) ^ sw)) =
              (_Float16)(accy[mt2][nt2][q] + abv);
        }
      }
    }
  }
  __syncthreads();
  // ---- ensemble GEMM (K=128) -> f16 out_pre + BN2 partials ----
  h8 ea[4];
#pragma unroll
  for (int ks = 0; ks < 4; ++ks)
    ea[ks] = *(const h8*)(wsH + EW_H + (mt * 16 + l15) * 128 + ks * 32 + l4 * 8);
  float eb[4];
#pragma unroll
  for (int q = 0; q < 4; ++q) eb[q] = ensb[mt * 16 + l4 * 4 + q];
  float lsum[4] = {0.f, 0.f, 0.f, 0.f}, lss[4] = {0.f, 0.f, 0.f, 0.f};
  u16* ob16 = (u16*)ws;
  for (int nt = nt0; nt < nt1; ++nt) {
    int s = nt * 16 + l15;
    int sw = (s & 7) << 4;
    f4 acc = {0.f, 0.f, 0.f, 0.f};
#pragma unroll
    for (int ks = 0; ks < 4; ++ks) {
      h8 b = *(const h8*)(sm + s * 256 + (((ks * 32 + l4 * 8) * 2) ^ sw));
      acc = __builtin_amdgcn_mfma_f32_16x16x32_f16(ea[ks], b, acc, 0, 0, 0);
    }
    size_t ob = (size_t)n * 204800 + (size_t)tile * 400 + s;
#pragma unroll
    for (int q = 0; q < 4; ++q) {
      int o = mt * 16 + l4 * 4 + q;
      union { _Float16 hf; u16 b; } cv;
      cv.hf = (_Float16)(acc[q] + eb[q]);
      ob16[ob + (size_t)o * 3200] = cv.b;
      float val = (float)cv.hf;
      lsum[q] += val;
      lss[q] += val * val;
    }
  }
  // wave-level reduce over the 16 l15 lanes, then one atomic per (l4,q)
#pragma unroll
  for (int q = 0; q < 4; ++q) {
#pragma unroll
    for (int d = 1; d < 16; d <<= 1) {
      lsum[q] += __shfl_xor(lsum[q], d);
      lss[q] += __shfl_xor(lss[q], d);
    }
  }
  if (l15 == 0) {
#pragma unroll
    for (int q = 0; q < 4; ++q) {
      int o = mt * 16 + l4 * 4 + q;
      atomicAdd(&redS[o], lsum[q]);
      atomicAdd(&redS[64 + o], lss[q]);
    }
  }
  __syncthreads();
  if (tid < 64) {
    ws[WS_BN2P + (size_t)bid * 128 + tid * 2] = redS[tid];
    ws[WS_BN2P + (size_t)bid * 128 + tid * 2 + 1] = redS[64 + tid];
  }
}

// ============ K9: BN2 reduce (parallel, one block per channel) ============
__global__ __launch_bounds__(256) void k_bn2(const float* __restrict__ g2,
                                             const float* __restrict__ b2,
                                             float* __restrict__ ws) {
  __shared__ float rs[256], rss[256];
  int o = blockIdx.x, tid = threadIdx.x;
  float s = 0.f, ss = 0.f;
  for (int b = tid; b < 1024; b += 256) {
    s += ws[WS_BN2P + (size_t)b * 128 + o * 2];
    ss += ws[WS_BN2P + (size_t)b * 128 + o * 2 + 1];
  }
  rs[tid] = s; rss[tid] = ss;
  __syncthreads();
  for (int st = 128; st > 0; st >>= 1) {
    if (tid < st) { rs[tid] += rs[tid + st]; rss[tid] += rss[tid + st]; }
    __syncthreads();
  }
  if (tid == 0) {
    float mu = rs[0] / MTOT;
    float var = rss[0] / MTOT - mu * mu;
    float a2 = g2[o] * rsqrtf(var + 1e-5f);
    ws[WS_PAR + o] = a2;
    ws[WS_PAR + 64 + o] = b2[o] - a2 * mu;
  }
}

// ============ K10: BN2 apply + residual + ReLU (reads f16 out_pre) ============
__global__ __launch_bounds__(256) void k_final(const float* __restrict__ x0,
                                               const float* __restrict__ ws,
                                               float* __restrict__ dout) {
  size_t g = (size_t)blockIdx.x * 256 + threadIdx.x;
  h4v p = reinterpret_cast<const h4v*>(ws)[g];
  float4 x = reinterpret_cast<const float4*>(x0)[g];
  int o = (int)((g * 4 / 3200) & 63);
  float a2 = ws[WS_PAR + o], bc = ws[WS_PAR + 64 + o];
  float4 r;
  r.x = fmaxf(fmaf(a2, (float)p[0], bc) + x.x, 0.f);
  r.y = fmaxf(fmaf(a2, (float)p[1], bc) + x.y, 0.f);
  r.z = fmaxf(fmaf(a2, (float)p[2], bc) + x.z, 0.f);
  r.w = fmaxf(fmaf(a2, (float)p[3], bc) + x.w, 0.f);
  reinterpret_cast<float4*>(dout)[g] = r;
}

extern "C" void kernel_launch(void* const* d_in, const int* in_sizes, int n_in,
                              void* d_out, int out_size, void* d_ws, size_t ws_size,
                              hipStream_t stream) {
  const float* x0    = (const float*)d_in[0];
  const float* DA    = (const float*)d_in[1];
  const float* Ag    = (const float*)d_in[2];
  const float* alpha = (const float*)d_in[3];
  const float* w1    = (const float*)d_in[4];
  const float* b1    = (const float*)d_in[5];
  const float* w2    = (const float*)d_in[6];
  const float* b2    = (const float*)d_in[7];
  const float* w3    = (const float*)d_in[8];
  const float* b3    = (const float*)d_in[9];
  const float* w4    = (const float*)d_in[10];
  const float* b4    = (const float*)d_in[11];
  const float* Lw    = (const float*)d_in[12];
  // d_in[13] Linear_bias: cancels under training-mode BN — unused
  const float* g0    = (const float*)d_in[14];
  const float* b0    = (const float*)d_in[15];
  const float* ensw  = (const float*)d_in[16];
  const float* ensb  = (const float*)d_in[17];
  const float* g2    = (const float*)d_in[18];
  const float* b2n   = (const float*)d_in[19];
  float* out = (float*)d_out;
  float* ws  = (float*)d_ws;

  hipFuncSetAttribute((const void*)kAB, hipFuncAttributeMaxDynamicSharedMemorySize, LDS_DYN);

  hipMemsetAsync(ws + WS_ATTB, 0, 204800 * sizeof(float), stream);
  hipMemsetAsync(out + DO_XM, 0, 204800 * sizeof(float), stream);
  k_gram<<<256, 512, 0, stream>>>(x0, out);
  k_prep<<<16, 256, 0, stream>>>(DA, w3, ensw, ws);
  k_att<<<384, 256, 0, stream>>>(out, w1, b1, w2, b2, w4, b4, Ag, alpha, b3, ws);
  k_gred<<<17, 256, 0, stream>>>(out);
  k_bnstat<<<12, 256, 0, stream>>>(out, Lw, g0, b0, ws);
  kAB<<<1024, 1024, LDS_DYN, stream>>>(x0, ws, ensb);
  k_bn2<<<64, 256, 0, stream>>>(g2, b2n, ws);
  k_final<<<25600, 256, 0, stream>>>(x0, ws, out);
}